// Round 6
// baseline (396.246 us; speedup 1.0000x reference)
//
#include <hip/hip_runtime.h>

#define LVAL 256
#define T    32
#define ST   36          // slab row stride (floats): 144 B, 16B-aligned
#define SLAB (T * ST)
#define NB   8
#define NEG  (-1e30f)

typedef float f32x4 __attribute__((ext_vector_type(4)));

// Compiler-only reorder fence (HW DS pipe is in-order within a wave).
#define SOFT_FENCE() asm volatile("" ::: "memory")

__device__ __forceinline__ size_t sidx(int b, int i, int e) {
    return ((size_t)b << 16) + (i << 8) + e;
}

// ---- coherent (MALL-level) accesses for cross-block data: bypass L1/L2 ----
__device__ __forceinline__ void st_coh4(float* p, f32x4 v) {
    asm volatile("global_store_dwordx4 %0, %1, off sc0 sc1"
                 :: "v"(p), "v"(v) : "memory");
}
__device__ __forceinline__ f32x4 ld_coh4(const float* p) {
    f32x4 v;
    asm volatile("global_load_dwordx4 %0, %1, off sc0 sc1\n\t"
                 "s_waitcnt vmcnt(0)"
                 : "=&v"(v) : "v"(p) : "memory");
    return v;
}
__device__ __forceinline__ void ld_coh4x4(const float* p,
                                          f32x4& a, f32x4& b, f32x4& c, f32x4& d) {
    asm volatile("global_load_dwordx4 %0, %4, off sc0 sc1\n\t"
                 "global_load_dwordx4 %1, %4, off offset:16 sc0 sc1\n\t"
                 "global_load_dwordx4 %2, %4, off offset:32 sc0 sc1\n\t"
                 "global_load_dwordx4 %3, %4, off offset:48 sc0 sc1\n\t"
                 "s_waitcnt vmcnt(0)"
                 : "=&v"(a), "=&v"(b), "=&v"(c), "=&v"(d)
                 : "v"(p) : "memory");
}

// VALU cross-lane max via DPP quad_perm
template<int CTRL>
__device__ __forceinline__ float dpp_max(float v) {
#if __has_builtin(__builtin_amdgcn_mov_dpp)
    int o = __builtin_amdgcn_mov_dpp(__builtin_bit_cast(int, v), CTRL, 0xF, 0xF, true);
    return fmaxf(v, __builtin_bit_cast(float, o));
#else
    return fmaxf(v, __shfl_xor(v, CTRL == 0xB1 ? 1 : 2));
#endif
}

__device__ __forceinline__ float red8(const f32x4 a, const f32x4 b,
                                      const f32x4 c, const f32x4 d) {
    float m0 = fmaxf(a.x + b.x, a.y + b.y);
    float m1 = fmaxf(a.z + b.z, a.w + b.w);
    float m2 = fmaxf(c.x + d.x, c.y + d.y);
    float m3 = fmaxf(c.z + d.z, c.w + d.w);
    return fmaxf(fmaxf(m0, m1), fmaxf(m2, m3));
}
__device__ __forceinline__ float red4(const f32x4 a, const f32x4 b) {
    float m0 = fmaxf(a.x + b.x, a.y + b.y);
    float m1 = fmaxf(a.z + b.z, a.w + b.w);
    return fmaxf(m0, m1);
}

// Phase 1: t[b,i,e] = max_c scores[b,i,e,c] -> f32 s[b][i][e], strict upper only.
__global__ __launch_bounds__(256) void phase1(const float* __restrict__ scores,
                                              float* __restrict__ s,
                                              int* __restrict__ bar) {
    if (blockIdx.x == 0 && blockIdx.y == 0) {
        for (int k = threadIdx.x; k < 2048; k += 256) bar[k] = 0;
    }
    const int i = blockIdx.x, b = blockIdx.y;
    const int sub = threadIdx.x & 15, slot = threadIdx.x >> 4;
    const float* row = scores + ((((size_t)b * LVAL + i) * LVAL) << 6);
    #pragma unroll 4
    for (int m0 = 0; m0 < LVAL; m0 += 16) {
        const int e = m0 + slot;
        if (e > i) {
            float4 v = *((const float4*)(row + ((size_t)e << 6)) + sub);
            float mx = fmaxf(fmaxf(v.x, v.y), fmaxf(v.z, v.w));
            #pragma unroll
            for (int d = 1; d < 16; d <<= 1) mx = fmaxf(mx, __shfl_xor(mx, d));
            if (sub == 0) s[sidx(b, i, e)] = mx;
        }
    }
}

// One wave-synchronous DP step inside a diagonal block (round 0).
template<int LP>
__device__ __forceinline__ void diag_step(int lane, int l,
                                          float (*cur)[ST], float (*curT)[ST],
                                          const float (*tb)[ST]) {
    const int cells = T - l;
    const int P = 1 << LP;
    const int c = lane >> LP, p = lane & (P - 1);
    const bool guard = c < cells;
    const int li = guard ? c : 0;
    const int le = guard ? c + l : 0;
    constexpr int NF = 8 >> LP;
    const float tv = tb[li][le];
    float acc = NEG;
    #pragma unroll
    for (int m = 0; m < NF; ++m) {
        const int k0 = 4 * (p + m * P);
        float4 cu = *(const float4*)&cur[li][k0];
        float4 ct = *(const float4*)&curT[le][k0];
        acc = fmaxf(acc, fmaxf(fmaxf(cu.x + ct.x, cu.y + ct.y),
                               fmaxf(cu.z + ct.z, cu.w + ct.w)));
    }
    acc = dpp_max<0xB1>(acc);                 // xor 1
    if (LP >= 2) acc = dpp_max<0x4E>(acc);    // xor 2
    const float v = acc + tv;
    if (guard && p == 0) cur[li][le] = v;
    if (guard && p == 1) curT[le][li] = v;
}

// Early (possibly-stale) full scan for edge step l, reduced to one scalar.
// Issued BEFORE the previous step's writes: misses only diag l-1, whose
// contributions are recovered by the late re-read of the 2 fresh chunks.
// All stale values are final-or-NEG (cells written exactly once) -> sound
// under max-idempotency.
__device__ __forceinline__ void e_early(int l, int c, int p,
        const float (*Ae)[ST], const float (*BeT)[ST],
        const float (*cur)[ST], const float (*curT)[ST],
        const float (*tb)[ST], const float (*pre)[ST],
        float& accOut, float& tvOut, float& prOut) {
    const int delta = l - (T - 1);
    const int ad = delta < 0 ? -delta : delta;
    const int cells = T - ad;
    const bool g = c < cells;
    const int li = g ? (delta < 0 ? c + ad : c) : 0;
    const int le = g ? li + delta : 0;
    tvOut = tb[li][le];
    prOut = pre[li][le];
    float acc = NEG;
    #pragma unroll
    for (int m = 0; m < 4; ++m) {
        const int k0 = 4 * (p + 2 * m);
        f32x4 a  = *(const f32x4*)&Ae[li][k0];
        f32x4 ct = *(const f32x4*)&curT[le][k0];
        f32x4 cu = *(const f32x4*)&cur[li][k0];
        f32x4 bt = *(const f32x4*)&BeT[le][k0];
        acc = fmaxf(acc, red8(a, ct, cu, bt));
    }
    accOut = acc;
}

// (max,+) GEMM of one 32x32 K-block: ag[i][j] = max(ag, AT[k][r0+i]+BW[k][c0+j])
__device__ __forceinline__ void gemm_blk(const float* ATs, const float (*BW)[ST],
                                         int r0, int c0, float (&ag)[4][4]) {
    const float (*AT)[ST] = (const float(*)[ST])ATs;
    #pragma unroll 4
    for (int k = 0; k < T; ++k) {
        f32x4 a4 = *(const f32x4*)&AT[k][r0];
        f32x4 b4 = *(const f32x4*)&BW[k][c0];
        #pragma unroll
        for (int i = 0; i < 4; ++i)
            #pragma unroll
            for (int j = 0; j < 4; ++j)
                ag[i][j] = fmaxf(ag[i][j], a4[i] + b4[j]);
    }
}

// Per-batch (8-block) barrier, fence-free (all cross-block data is sc0/sc1).
__device__ __forceinline__ void batch_barrier(int* __restrict__ bar, int b,
                                              int tid, int ep) {
    asm volatile("s_waitcnt vmcnt(0)" ::: "memory");
    __syncthreads();
    if (tid == 0) {
        int* cnt  = bar + b * 256;
        int* flag = bar + b * 256 + 64;
        int prev = __hip_atomic_fetch_add(cnt, 1, __ATOMIC_RELAXED,
                                          __HIP_MEMORY_SCOPE_AGENT);
        if ((prev & (NB - 1)) == NB - 1) {
            __hip_atomic_store(flag, ep, __ATOMIC_RELAXED, __HIP_MEMORY_SCOPE_AGENT);
        } else {
            int guard = 0;
            while (__hip_atomic_load(flag, __ATOMIC_RELAXED,
                                     __HIP_MEMORY_SCOPE_AGENT) < ep) {
                __builtin_amdgcn_s_sleep(2);
                if (++guard > (1 << 22)) break;
            }
        }
    }
    __syncthreads();
}

__global__ __launch_bounds__(256) void dp_fused(float* __restrict__ s,
                                                const int* __restrict__ lens,
                                                float* __restrict__ out,
                                                int* __restrict__ bar) {
    __shared__ __align__(16) float smem[14 * SLAB];      // 64512 B
    float* ATb = smem;                                   // 6 persistent A^T slabs
    float (*Ae)[ST]  = (float(*)[ST])(smem + 6 * SLAB);
    float (*tb)[ST]  = (float(*)[ST])(smem + 7 * SLAB);
    float (*BeT)[ST] = (float(*)[ST])(smem + 8 * SLAB);
    float (*cur)[ST] = (float(*)[ST])(smem + 9 * SLAB);
    float* BWb = smem + 10 * SLAB;                       // 4 per-wave GEMM slabs
    float (*pre)[ST] = (float(*)[ST])BWb;                // = BW0 (after combine)

    const int b  = blockIdx.x & 7;
    const int bi = blockIdx.x >> 3;
    const int tid = threadIdx.x, wid = tid >> 6, lane = tid & 63;
    const int lr = tid >> 5, lc = tid & 31;
    const int grow = lane >> 1, gc = (lane & 1) * 16;
    const int gly = lane >> 3, glx = lane & 7, r0 = 4 * gly, c0 = 4 * glx;
    const int trow = tid >> 3, tc4 = (tid & 7) * 4;
    float (*BW)[ST] = (float(*)[ST])(BWb + wid * SLAB);
    const int c = lane >> 1, p = lane & 1;

    // next-round operands preloaded into registers during the edge window
    f32x4 pbA[4], pbB[4];        // waves 1-3: B-blocks K=bi+1+wid, bi+4+wid
    f32x4 tpb[4], bpb[4];        // wave1: tb;  wave2: BeT diag

    // ---- round 0: wave0 diag DP into Ae; waves 1-3 prefetch tb(D=1)
    if (wid == 0) {
        float (*curT0)[ST] = (float(*)[ST])(BWb + 1 * SLAB);
        float (*t0)[ST]    = (float(*)[ST])(BWb + 2 * SLAB);
        const float4 negv = make_float4(NEG, NEG, NEG, NEG);
        #pragma unroll
        for (int j = 0; j < 4; ++j) {
            float4 v = *(const float4*)&s[sidx(b, bi * T + grow, bi * T + gc + 4 * j)];
            *(float4*)&t0[grow][gc + 4 * j]    = v;
            *(float4*)&Ae[grow][gc + 4 * j]    = negv;
            *(float4*)&curT0[grow][gc + 4 * j] = negv;
        }
        SOFT_FENCE();
        if (lane < T - 1) {                    // w == 1 diagonal = t (final)
            float v = t0[lane][lane + 1];
            Ae[lane][lane + 1] = v;
            curT0[lane + 1][lane] = v;
        }
        SOFT_FENCE();
        #pragma unroll 1
        for (int l = 2; l < T; ++l) {
            if (T - l <= 16) diag_step<2>(lane, l, Ae, curT0, t0);
            else             diag_step<1>(lane, l, Ae, curT0, t0);
            SOFT_FENCE();
        }
        #pragma unroll
        for (int j = 0; j < 4; ++j)            // publish diag (NEG lower kept)
            st_coh4(&s[sidx(b, bi * T + grow, bi * T + gc + 4 * j)],
                    *(const f32x4*)&Ae[grow][gc + 4 * j]);
    } else if (bi + 1 < NB) {
        for (int idx = tid - 64; idx < 256; idx += 192) {
            const int row = idx >> 3, c4 = (idx & 7) * 4;
            *(float4*)&tb[row][c4] =
                *(const float4*)&s[sidx(b, bi * T + row, (bi + 1) * T + c4)];
        }
    }

    // ---- rounds 1..7 ----
    #pragma unroll 1
    for (int D = 1; D < NB; ++D) {
        batch_barrier(bar, b, tid, D);
        const int be = bi + D;
        if (be < NB) {
            if (D == 1) {                      // diag be only final after barrier 1
                f32x4 v = ld_coh4(&s[sidx(b, be * T + trow, be * T + tc4)]);
                BeT[tc4 + 0][trow] = (trow < tc4 + 0) ? v[0] : NEG;
                BeT[tc4 + 1][trow] = (trow < tc4 + 1) ? v[1] : NEG;
                BeT[tc4 + 2][trow] = (trow < tc4 + 2) ? v[2] : NEG;
                BeT[tc4 + 3][trow] = (trow < tc4 + 3) ? v[3] : NEG;
            }
            // GEMM: wave0 handles only the fresh block K=bi+1 (published during
            // round D-1 -> must load post-barrier); waves 1-3 use registers
            // preloaded during the previous round's edge window.
            const int nw = (D - 1 < 4) ? (D - 1) : 4;
            float ag[4][4];
            #pragma unroll
            for (int i = 0; i < 4; ++i)
                #pragma unroll
                for (int j = 0; j < 4; ++j) ag[i][j] = NEG;
            if (D >= 2) {
                if (wid == 0) {
                    f32x4 b0, b1, b2, b3;
                    ld_coh4x4(&s[sidx(b, (bi + 1) * T + grow, be * T + gc)],
                              b0, b1, b2, b3);
                    *(f32x4*)&BW[grow][gc + 0]  = b0;
                    *(f32x4*)&BW[grow][gc + 4]  = b1;
                    *(f32x4*)&BW[grow][gc + 8]  = b2;
                    *(f32x4*)&BW[grow][gc + 12] = b3;
                    SOFT_FENCE();
                    gemm_blk(ATb + 0, BW, r0, c0, ag);
                } else {
                    if (wid <= D - 2) {        // K = bi+1+wid
                        #pragma unroll
                        for (int j = 0; j < 4; ++j)
                            *(f32x4*)&BW[grow][gc + 4 * j] = pbA[j];
                        SOFT_FENCE();
                        gemm_blk(ATb + wid * SLAB, BW, r0, c0, ag);
                        SOFT_FENCE();
                    }
                    if (wid + 3 <= D - 2) {    // K = bi+4+wid
                        #pragma unroll
                        for (int j = 0; j < 4; ++j)
                            *(f32x4*)&BW[grow][gc + 4 * j] = pbB[j];
                        SOFT_FENCE();
                        gemm_blk(ATb + (wid + 3) * SLAB, BW, r0, c0, ag);
                    }
                }
            }
            if (wid < nw) {
                #pragma unroll
                for (int i = 0; i < 4; ++i)
                    *(f32x4*)&BW[r0 + i][c0] =
                        f32x4{ag[i][0], ag[i][1], ag[i][2], ag[i][3]};
            }
            __syncthreads();
            #pragma unroll
            for (int r = 0; r < 4; ++r) {      // combine wave partials -> pre (=BW0)
                const int row = lr + 8 * r;
                float v = NEG;
                for (int w2 = 0; w2 < nw; ++w2)
                    v = fmaxf(v, BWb[w2 * SLAB + row * ST + lc]);
                pre[row][lc] = v;
            }
            __syncthreads();
            float (*curT)[ST] = (D == NB - 1) ? (float(*)[ST])(BWb + 1 * SLAB)
                                              : (float(*)[ST])(ATb + (D - 1) * SLAB);
            #pragma unroll
            for (int r = 0; r < 4; ++r) {
                const int row = lr + 8 * r;
                cur[row][lc]  = NEG;
                curT[row][lc] = NEG;
            }
            __syncthreads();
            if (wid == 0) {
                // ---- pipelined edge pass: stale full scan issued one step
                // early + scalar-reduced; 2 fresh chunks (+static partners)
                // re-read late. No cross-lane ops on the critical chain.
                float accN, tvN, prN;
                e_early(0, c, p, Ae, BeT, cur, curT, tb, pre, accN, tvN, prN);
                SOFT_FENCE();
                float accP = accN, tvC = tvN, prC = prN;
                #pragma unroll 1
                for (int l = 0; l < 2 * T - 1; ++l) {
                    const int delta = l - (T - 1);
                    const int ad = delta < 0 ? -delta : delta;
                    const int cells = T - ad;
                    const bool g = c < cells;
                    const int li = g ? (delta < 0 ? c + ad : c) : 0;
                    const int le = g ? li + delta : 0;
                    // late reads: fresh diag l-1 chunks (clamped; idempotent)
                    const int cfA = ((li + 1 < T ? li + 1 : T - 1) >> 2) << 2;
                    const int cfB = ((le > 0 ? le - 1 : 0) >> 2) << 2;
                    f32x4 lA  = *(const f32x4*)&Ae[li][cfA];
                    f32x4 lCT = *(const f32x4*)&curT[le][cfA];
                    f32x4 lCU = *(const f32x4*)&cur[li][cfB];
                    f32x4 lBT = *(const f32x4*)&BeT[le][cfB];
                    SOFT_FENCE();
                    // early scan for step l+1 (stale ok: before writes of l)
                    if (l + 1 < 2 * T - 1)
                        e_early(l + 1, c, p, Ae, BeT, cur, curT, tb, pre,
                                accN, tvN, prN);
                    SOFT_FENCE();
                    // finish step l
                    float acc = fmaxf(accP, prC);
                    acc = fmaxf(acc, red4(lA, lCT));
                    acc = fmaxf(acc, red4(lCU, lBT));
                    acc = dpp_max<0xB1>(acc);
                    const float v = (D == 1 && l == 0) ? tvC : acc + tvC;
                    if (g && p == 0) cur[li][le] = v;
                    if (g && p == 1) curT[le][li] = v;
                    SOFT_FENCE();
                    accP = accN; tvC = tvN; prC = prN;
                }
            } else if (be + 1 < NB) {
                // preloads for round D+1 during the edge window (VMEM only:
                // no DS contention with wave0's DS-bound edge pass). All
                // targeted blocks were published before barrier D -> race-free.
                if (wid <= D - 1)              // K = bi+1+wid for next round
                    ld_coh4x4(&s[sidx(b, (bi + 1 + wid) * T + grow, (be + 1) * T + gc)],
                              pbA[0], pbA[1], pbA[2], pbA[3]);
                if (wid + 3 <= D - 1)          // K = bi+4+wid for next round
                    ld_coh4x4(&s[sidx(b, (bi + 4 + wid) * T + grow, (be + 1) * T + gc)],
                              pbB[0], pbB[1], pbB[2], pbB[3]);
                if (wid == 1) {                // next tb (phase-1 data: cached path)
                    #pragma unroll
                    for (int j = 0; j < 4; ++j)
                        tpb[j] = *(const f32x4*)&s[sidx(b, bi * T + grow,
                                                        (be + 1) * T + gc + 4 * j)];
                }
                if (wid == 2) {                // next BeT diag (DP output: coh)
                    #pragma unroll
                    for (int j = 0; j < 4; ++j)
                        bpb[j] = ld_coh4(&s[sidx(b, (be + 1) * T + grow,
                                                 (be + 1) * T + gc + 4 * j)]);
                }
            }
            __syncthreads();
            {                                  // publish (bi,be) for other rows
                f32x4 pv = *(const f32x4*)&cur[trow][tc4];
                st_coh4(&s[sidx(b, bi * T + trow, be * T + tc4)], pv);
            }
            if (be + 1 < NB) {                 // write next-round tb/BeT from regs
                if (wid == 1) {
                    #pragma unroll
                    for (int j = 0; j < 4; ++j)
                        *(f32x4*)&tb[grow][gc + 4 * j] = tpb[j];
                }
                if (wid == 2) {
                    #pragma unroll
                    for (int j = 0; j < 4; ++j)
                        #pragma unroll
                        for (int k = 0; k < 4; ++k) {
                            const int col = gc + 4 * j + k;
                            BeT[col][grow] = (grow < col) ? bpb[j][k] : NEG;
                        }
                }
            }
        }
    }

    // Fused finalize: block (b,0) owns row 0, everything needed is in its LDS.
    if (bi == 0 && tid == 0) {
        int len = lens[b];
        len = len < 1 ? 1 : (len > LVAL - 1 ? LVAL - 1 : len);
        const int K = len >> 5, off = len & 31;
        float r;
        if (K == 0)           r = Ae[0][off];
        else if (K == NB - 1) r = cur[0][off];
        else                  r = ATb[(K - 1) * SLAB + off * ST];
        out[b] = r;
    }
}

extern "C" void kernel_launch(void* const* d_in, const int* in_sizes, int n_in,
                              void* d_out, int out_size, void* d_ws, size_t ws_size,
                              hipStream_t stream) {
    const float* scores = (const float*)d_in[0];
    const int*   lens   = (const int*)d_in[1];
    float*       out    = (float*)d_out;
    float*       s      = (float*)d_ws;               // 8 * 256 * 256 f32 = 2 MB
    int*         bar    = (int*)((char*)d_ws + ((size_t)(8) << 16) * sizeof(float));

    phase1<<<dim3(LVAL, 8), 256, 0, stream>>>(scores, s, bar);
    dp_fused<<<64, 256, 0, stream>>>(s, lens, out, bar);
}

// Round 7
// 339.116 us; speedup vs baseline: 1.1685x; 1.1685x over previous
//
#include <hip/hip_runtime.h>

#define LVAL 256
#define T    32
#define ST   36          // slab row stride (floats): 144 B, 16B-aligned
#define SLAB (T * ST)
#define NB   8
#define NEG  (-1e30f)

typedef float f32x4 __attribute__((ext_vector_type(4)));

// Compiler-only reorder fence (HW DS pipe is in-order within a wave).
#define SOFT_FENCE() asm volatile("" ::: "memory")

__device__ __forceinline__ size_t sidx(int b, int i, int e) {
    return ((size_t)b << 16) + (i << 8) + e;
}

// ---- coherent (MALL-level) accesses for cross-block data: bypass L1/L2 ----
__device__ __forceinline__ void st_coh4(float* p, f32x4 v) {
    asm volatile("global_store_dwordx4 %0, %1, off sc0 sc1"
                 :: "v"(p), "v"(v) : "memory");
}
__device__ __forceinline__ f32x4 ld_coh4(const float* p) {
    f32x4 v;
    asm volatile("global_load_dwordx4 %0, %1, off sc0 sc1\n\t"
                 "s_waitcnt vmcnt(0)"
                 : "=&v"(v) : "v"(p) : "memory");
    return v;
}
__device__ __forceinline__ void ld_coh4x4(const float* p,
                                          f32x4& a, f32x4& b, f32x4& c, f32x4& d) {
    asm volatile("global_load_dwordx4 %0, %4, off sc0 sc1\n\t"
                 "global_load_dwordx4 %1, %4, off offset:16 sc0 sc1\n\t"
                 "global_load_dwordx4 %2, %4, off offset:32 sc0 sc1\n\t"
                 "global_load_dwordx4 %3, %4, off offset:48 sc0 sc1\n\t"
                 "s_waitcnt vmcnt(0)"
                 : "=&v"(a), "=&v"(b), "=&v"(c), "=&v"(d)
                 : "v"(p) : "memory");
}
__device__ __forceinline__ void st_coh1(int* p, int v) {
    asm volatile("global_store_dword %0, %1, off sc0 sc1"
                 :: "v"(p), "v"(v) : "memory");
}
__device__ __forceinline__ int ld_coh1(const int* p) {
    int v;
    asm volatile("global_load_dword %0, %1, off sc0 sc1\n\t"
                 "s_waitcnt vmcnt(0)"
                 : "=&v"(v) : "v"(p) : "memory");
    return v;
}
// tight spin on a producer flag (MALL RT poll ~0.3us; loud bailout on bug)
__device__ __forceinline__ void spin_flag(int* f) {
    int guard = 0;
    while (ld_coh1(f) == 0) {
        if (++guard > (1 << 20)) break;
    }
}

// VALU cross-lane max via DPP quad_perm
template<int CTRL>
__device__ __forceinline__ float dpp_max(float v) {
#if __has_builtin(__builtin_amdgcn_mov_dpp)
    int o = __builtin_amdgcn_mov_dpp(__builtin_bit_cast(int, v), CTRL, 0xF, 0xF, true);
    return fmaxf(v, __builtin_bit_cast(float, o));
#else
    return fmaxf(v, __shfl_xor(v, CTRL == 0xB1 ? 1 : 2));
#endif
}

// Phase 1: t[b,i,e] = max_c scores[b,i,e,c] -> f32 s[b][i][e], strict upper only.
__global__ __launch_bounds__(256) void phase1(const float* __restrict__ scores,
                                              float* __restrict__ s,
                                              int* __restrict__ bar) {
    if (blockIdx.x == 0 && blockIdx.y == 0) {
        for (int k = threadIdx.x; k < 2048; k += 256) bar[k] = 0;
    }
    const int i = blockIdx.x, b = blockIdx.y;
    const int sub = threadIdx.x & 15, slot = threadIdx.x >> 4;
    const float* row = scores + ((((size_t)b * LVAL + i) * LVAL) << 6);
    #pragma unroll 4
    for (int m0 = 0; m0 < LVAL; m0 += 16) {
        const int e = m0 + slot;
        if (e > i) {
            float4 v = *((const float4*)(row + ((size_t)e << 6)) + sub);
            float mx = fmaxf(fmaxf(v.x, v.y), fmaxf(v.z, v.w));
            #pragma unroll
            for (int d = 1; d < 16; d <<= 1) mx = fmaxf(mx, __shfl_xor(mx, d));
            if (sub == 0) s[sidx(b, i, e)] = mx;
        }
    }
}

// One wave-synchronous DP step inside a diagonal block (round 0).
template<int LP>
__device__ __forceinline__ void diag_step(int lane, int l,
                                          float (*cur)[ST], float (*curT)[ST],
                                          const float (*tb)[ST]) {
    const int cells = T - l;
    const int P = 1 << LP;
    const int c = lane >> LP, p = lane & (P - 1);
    const bool guard = c < cells;
    const int li = guard ? c : 0;
    const int le = guard ? c + l : 0;
    constexpr int NF = 8 >> LP;
    const float tv = tb[li][le];
    float acc = NEG;
    #pragma unroll
    for (int m = 0; m < NF; ++m) {
        const int k0 = 4 * (p + m * P);
        float4 cu = *(const float4*)&cur[li][k0];
        float4 ct = *(const float4*)&curT[le][k0];
        acc = fmaxf(acc, fmaxf(fmaxf(cu.x + ct.x, cu.y + ct.y),
                               fmaxf(cu.z + ct.z, cu.w + ct.w)));
    }
    acc = dpp_max<0xB1>(acc);                 // xor 1
    if (LP >= 2) acc = dpp_max<0x4E>(acc);    // xor 2
    const float v = acc + tv;
    if (guard && p == 0) cur[li][le] = v;
    if (guard && p == 1) curT[le][li] = v;
}

// One wave-synchronous edge step of round D. All splits scanned maskless:
// Ae/BeT pre-masked with NEG, cur/curT hold NEG in not-yet-final slots.
template<int LP>
__device__ __forceinline__ void edge_step(int lane, int l, int D,
                                          const float (*Ae)[ST], const float (*BeT)[ST],
                                          float (*cur)[ST], float (*curT)[ST],
                                          const float (*tb)[ST], const float (*pre)[ST]) {
    const int delta = l - (T - 1);
    const int ad = delta < 0 ? -delta : delta;
    const int cells = T - ad;
    const int P = 1 << LP;
    const int c = lane >> LP, p = lane & (P - 1);
    const bool guard = c < cells;
    const int li = guard ? (delta < 0 ? c + ad : c) : 0;
    const int le = guard ? li + delta : 0;
    constexpr int NF = 8 >> LP;
    const float tv = tb[li][le];
    float acc = pre[li][le];                   // middle-K GEMM partial (NEG if none)
    #pragma unroll
    for (int m = 0; m < NF; ++m) {
        const int k0 = 4 * (p + m * P);
        float4 a  = *(const float4*)&Ae[li][k0];     // split in left edge block
        float4 ct = *(const float4*)&curT[le][k0];
        float4 cu = *(const float4*)&cur[li][k0];    // split in right edge block
        float4 bt = *(const float4*)&BeT[le][k0];
        float s0 = fmaxf(fmaxf(a.x + ct.x, a.y + ct.y), fmaxf(a.z + ct.z, a.w + ct.w));
        float s1 = fmaxf(fmaxf(cu.x + bt.x, cu.y + bt.y), fmaxf(cu.z + bt.z, cu.w + bt.w));
        acc = fmaxf(acc, fmaxf(s0, s1));
    }
    acc = dpp_max<0xB1>(acc);
    if (LP >= 2) acc = dpp_max<0x4E>(acc);
    const float v = (D == 1 && l == 0) ? tv : acc + tv;   // w==1 cell: value is t
    if (guard && p == 0) cur[li][le] = v;
    if (guard && p == 1) curT[le][li] = v;
}

// (max,+) GEMM of one 32x32 K-block: ag[i][j] = max(ag, AT[k][r0+i]+BW[k][c0+j])
__device__ __forceinline__ void gemm_blk(const float* ATs, const float (*BW)[ST],
                                         int r0, int c0, float (&ag)[4][4]) {
    const float (*AT)[ST] = (const float(*)[ST])ATs;
    #pragma unroll 4
    for (int k = 0; k < T; ++k) {
        f32x4 a4 = *(const f32x4*)&AT[k][r0];
        f32x4 b4 = *(const f32x4*)&BW[k][c0];
        #pragma unroll
        for (int i = 0; i < 4; ++i)
            #pragma unroll
            for (int j = 0; j < 4; ++j)
                ag[i][j] = fmaxf(ag[i][j], a4[i] + b4[j]);
    }
}

// Self-timed dataflow: block (b,bi) computes tiles (bi,bi+D), D=0..NB-1-bi.
// No global barrier: per-tile flags (MALL-coherent) release consumers. The
// dependency DAG is acyclic (tile (bi,be) consumes only tiles with smaller
// width), so the cascade is deadlock-free; spins carry loud bailouts.
__global__ __launch_bounds__(256) void dp_fused(float* __restrict__ s,
                                                const int* __restrict__ lens,
                                                float* __restrict__ out,
                                                int* __restrict__ bar) {
    __shared__ __align__(16) float smem[14 * SLAB];      // 64512 B
    float* ATb = smem;                                   // 6 persistent A^T slabs
    float (*Ae)[ST]  = (float(*)[ST])(smem + 6 * SLAB);
    float (*tb)[ST]  = (float(*)[ST])(smem + 7 * SLAB);
    float (*BeT)[ST] = (float(*)[ST])(smem + 8 * SLAB);
    float (*cur)[ST] = (float(*)[ST])(smem + 9 * SLAB);
    float* BWb = smem + 10 * SLAB;                       // 4 per-wave GEMM slabs
    float (*pre)[ST] = (float(*)[ST])BWb;                // = BW0 (after combine)

    const int b  = blockIdx.x & 7;
    const int bi = blockIdx.x >> 3;
    const int tid = threadIdx.x, wid = tid >> 6, lane = tid & 63;
    const int lr = tid >> 5, lc = tid & 31;
    const int grow = lane >> 1, gc = (lane & 1) * 16;
    const int gly = lane >> 3, glx = lane & 7, r0 = 4 * gly, c0 = 4 * glx;
    const int trow = tid >> 3, tc4 = (tid & 7) * 4;
    float (*BW)[ST] = (float(*)[ST])(BWb + wid * SLAB);
    int* flags = bar + b * 64;                 // flags[K*8 + e] per tile (K,e)

    f32x4 tpb[4], bpb[4];                      // wave1: next tb; wave2: next BeT

    // ---- round 0: wave0 diag DP into Ae; waves 1-3 prefetch tb(D=1)
    if (wid == 0) {
        float (*curT0)[ST] = (float(*)[ST])(BWb + 1 * SLAB);
        float (*t0)[ST]    = (float(*)[ST])(BWb + 2 * SLAB);
        const float4 negv = make_float4(NEG, NEG, NEG, NEG);
        #pragma unroll
        for (int j = 0; j < 4; ++j) {
            float4 v = *(const float4*)&s[sidx(b, bi * T + grow, bi * T + gc + 4 * j)];
            *(float4*)&t0[grow][gc + 4 * j]    = v;
            *(float4*)&Ae[grow][gc + 4 * j]    = negv;
            *(float4*)&curT0[grow][gc + 4 * j] = negv;
        }
        SOFT_FENCE();
        if (lane < T - 1) {                    // w == 1 diagonal = t (final)
            float v = t0[lane][lane + 1];
            Ae[lane][lane + 1] = v;
            curT0[lane + 1][lane] = v;
        }
        SOFT_FENCE();
        #pragma unroll 1
        for (int l = 2; l < T; ++l) {
            if (T - l <= 16) diag_step<2>(lane, l, Ae, curT0, t0);
            else             diag_step<1>(lane, l, Ae, curT0, t0);
            SOFT_FENCE();
        }
        #pragma unroll
        for (int j = 0; j < 4; ++j)            // publish diag (NEG lower kept)
            st_coh4(&s[sidx(b, bi * T + grow, bi * T + gc + 4 * j)],
                    *(const f32x4*)&Ae[grow][gc + 4 * j]);
        asm volatile("s_waitcnt vmcnt(0)" ::: "memory");
        if (lane == 0) st_coh1(&flags[bi * 8 + bi], 1);   // release diag tile
    } else if (bi + 1 < NB) {
        for (int idx = tid - 64; idx < 256; idx += 192) {
            const int row = idx >> 3, c4 = (idx & 7) * 4;
            *(float4*)&tb[row][c4] =
                *(const float4*)&s[sidx(b, bi * T + row, (bi + 1) * T + c4)];
        }
    }

    // ---- rounds 1..NB-1-bi (blocks exit when their row is done) ----
    #pragma unroll 1
    for (int D = 1; D <= NB - 1 - bi; ++D) {
        const int be = bi + D;
        // head: wait exactly the tiles this round consumes
        if (tid == 0) {
            for (int K = bi + 1; K < be; ++K) spin_flag(&flags[K * 8 + be]);
            if (D == 1) spin_flag(&flags[be * 8 + be]);
        }
        __syncthreads();
        if (D == 1) {                          // diag be: head load (flag waited)
            f32x4 v = ld_coh4(&s[sidx(b, be * T + trow, be * T + tc4)]);
            BeT[tc4 + 0][trow] = (trow < tc4 + 0) ? v[0] : NEG;
            BeT[tc4 + 1][trow] = (trow < tc4 + 1) ? v[1] : NEG;
            BeT[tc4 + 2][trow] = (trow < tc4 + 2) ? v[2] : NEG;
            BeT[tc4 + 3][trow] = (trow < tc4 + 3) ? v[3] : NEG;
        }
        // GEMM over middle K blocks: A^T resident in LDS, B staged per wave
        const int nw = (D - 1 < 4) ? (D - 1) : 4;
        float ag[4][4];
        #pragma unroll
        for (int i = 0; i < 4; ++i)
            #pragma unroll
            for (int j = 0; j < 4; ++j) ag[i][j] = NEG;
        for (int K = bi + 1 + wid; K < be; K += 4) {
            const float (*AT)[ST] = (const float(*)[ST])(ATb + (K - bi - 1) * SLAB);
            f32x4 b0, b1, b2, b3;
            ld_coh4x4(&s[sidx(b, K * T + grow, be * T + gc)], b0, b1, b2, b3);
            *(f32x4*)&BW[grow][gc + 0]  = b0;
            *(f32x4*)&BW[grow][gc + 4]  = b1;
            *(f32x4*)&BW[grow][gc + 8]  = b2;
            *(f32x4*)&BW[grow][gc + 12] = b3;
            SOFT_FENCE();
            gemm_blk((const float*)AT, BW, r0, c0, ag);
            SOFT_FENCE();
        }
        if (wid < nw) {
            #pragma unroll
            for (int i = 0; i < 4; ++i)
                *(f32x4*)&BW[r0 + i][c0] =
                    f32x4{ag[i][0], ag[i][1], ag[i][2], ag[i][3]};
        }
        __syncthreads();
        #pragma unroll
        for (int r = 0; r < 4; ++r) {          // combine wave partials -> pre (=BW0)
            const int row = lr + 8 * r;
            float v = NEG;
            for (int w2 = 0; w2 < nw; ++w2)
                v = fmaxf(v, BWb[w2 * SLAB + row * ST + lc]);
            pre[row][lc] = v;
        }
        __syncthreads();
        float (*curT)[ST] = (D == NB - 1) ? (float(*)[ST])(BWb + 1 * SLAB)
                                          : (float(*)[ST])(ATb + (D - 1) * SLAB);
        #pragma unroll
        for (int r = 0; r < 4; ++r) {
            const int row = lr + 8 * r;
            cur[row][lc]  = NEG;
            curT[row][lc] = NEG;
        }
        __syncthreads();
        if (wid == 0) {                        // wave-synchronous edge pass
            #pragma unroll 1
            for (int l = 0; l < 2 * T - 1; ++l) {
                const int ad0 = (l < T - 1) ? (T - 1 - l) : (l - (T - 1));
                if (ad0 >= 16) edge_step<2>(lane, l, D, Ae, BeT, cur, curT, tb, pre);
                else           edge_step<1>(lane, l, D, Ae, BeT, cur, curT, tb, pre);
                SOFT_FENCE();
            }
        } else if (be + 1 < NB) {
            // register preloads for round D+1 during the edge window
            if (wid == 1) {                    // next tb (phase-1 data: cached)
                #pragma unroll
                for (int j = 0; j < 4; ++j)
                    tpb[j] = *(const f32x4*)&s[sidx(b, bi * T + grow,
                                                    (be + 1) * T + gc + 4 * j)];
            }
            if (wid == 2) {                    // next BeT diag (flag-gated coh)
                spin_flag(&flags[(be + 1) * 8 + (be + 1)]);
                #pragma unroll
                for (int j = 0; j < 4; ++j)
                    bpb[j] = ld_coh4(&s[sidx(b, (be + 1) * T + grow,
                                             (be + 1) * T + gc + 4 * j)]);
            }
        }
        __syncthreads();
        {                                      // publish (bi,be) for other rows
            f32x4 pv = *(const f32x4*)&cur[trow][tc4];
            st_coh4(&s[sidx(b, bi * T + trow, be * T + tc4)], pv);
        }
        asm volatile("s_waitcnt vmcnt(0)" ::: "memory");
        __syncthreads();                       // all stores drained block-wide
        if (tid == 0) st_coh1(&flags[bi * 8 + be], 1);   // release tile
        if (be + 1 < NB) {                     // write next-round tb/BeT from regs
            if (wid == 1) {
                #pragma unroll
                for (int j = 0; j < 4; ++j)
                    *(f32x4*)&tb[grow][gc + 4 * j] = tpb[j];
            }
            if (wid == 2) {
                #pragma unroll
                for (int j = 0; j < 4; ++j)
                    #pragma unroll
                    for (int k = 0; k < 4; ++k) {
                        const int col = gc + 4 * j + k;
                        BeT[col][grow] = (grow < col) ? bpb[j][k] : NEG;
                    }
            }
        }
    }

    // Fused finalize: block (b,0) owns row 0, everything needed is in its LDS.
    if (bi == 0 && tid == 0) {
        int len = lens[b];
        len = len < 1 ? 1 : (len > LVAL - 1 ? LVAL - 1 : len);
        const int K = len >> 5, off = len & 31;
        float r;
        if (K == 0)           r = Ae[0][off];
        else if (K == NB - 1) r = cur[0][off];
        else                  r = ATb[(K - 1) * SLAB + off * ST];
        out[b] = r;
    }
}

extern "C" void kernel_launch(void* const* d_in, const int* in_sizes, int n_in,
                              void* d_out, int out_size, void* d_ws, size_t ws_size,
                              hipStream_t stream) {
    const float* scores = (const float*)d_in[0];
    const int*   lens   = (const int*)d_in[1];
    float*       out    = (float*)d_out;
    float*       s      = (float*)d_ws;               // 8 * 256 * 256 f32 = 2 MB
    int*         bar    = (int*)((char*)d_ws + ((size_t)(8) << 16) * sizeof(float));

    phase1<<<dim3(LVAL, 8), 256, 0, stream>>>(scores, s, bar);
    dp_fused<<<64, 256, 0, stream>>>(s, lens, out, bar);
}